// Round 9
// baseline (913.721 us; speedup 1.0000x reference)
//
#include <hip/hip_runtime.h>

// T2ICrossAttentionPool on MI355X.
// Identities: w12[c,i,w] = sum_r attn*Sraw;  |wctx|^2 = a^T G a with
//   G = exact fp32 diag (register math) + off-diag G' bf16 (MFMA quadratic form).
// R8 post-mortem: fragment-order streaming killed the LDS wall (conflicts
//   3.6e8 -> 7.4e6; 638 us) but the K-loop is ~50% issue-stalled: 2-stage
//   pipeline can't cover ~250cyc L2 latency with 2 waves/SIMD, and mlim
//   guards make the unrolled loop branchy (conservative waitcnts).
// R9: (1) 3-stage register pipeline (30 frag regs = 120 VGPR + 96 AGPR =
//   236 <= 256 -> still 2 waves/EU); (2) kloop templated on MLIM (switch
//   1..4) -> straight-line loads/MFMAs, exact traffic; (3) w1 fused into
//   caps_frag prep (one pass over caps).

#define NIMG 256
#define NREG 36
#define DIM 1024
#define NCAP 256
#define MAXW 60
#define WPAD 64

typedef short bf16x8 __attribute__((ext_vector_type(8)));
typedef float f32x4 __attribute__((ext_vector_type(4)));

__device__ __forceinline__ unsigned short f2bf(float f) {
  unsigned u = __float_as_uint(f);
  u += 0x7FFF + ((u >> 16) & 1);   // round-to-nearest-even
  return (unsigned short)(u >> 16);
}

// ---- prep: caps -> A fragments (masked rows zero) + w1 (fp32 row norms) ----
// Layout: qbfF[(((c*32 + k32)*4 + mt)*64 + lane)*8 + j]
//   = q[c][m = mt*16 + (lane&15)][k = k32*32 + (lane>>4)*8 + j]
// Grid = NCAP, block = 256 (wave wv == mt).
__global__ void k_prep_caps_frag(const float* __restrict__ caps, const int* __restrict__ cap_lens,
                                 unsigned short* __restrict__ qbfF, float* __restrict__ w1) {
  const int c = blockIdx.x;
  const int t = threadIdx.x;
  const int mt = t >> 6;
  const int lane = t & 63;
  const int l15 = lane & 15;
  const int q = lane >> 4;
  const int m = mt * 16 + l15;
  const int clen = cap_lens[c];
  const bool valid = (m < clen) && (m < MAXW);
  const float* src0 = caps + ((size_t)c * MAXW + m) * DIM + q * 8;
  unsigned short* dst0 = qbfF + ((size_t)((c * 32) * 4 + mt) * 64 + lane) * 8;
  float ss = 0.f;
  for (int k32 = 0; k32 < 32; ++k32) {
    float4 v0 = make_float4(0.f, 0.f, 0.f, 0.f), v1 = v0;
    if (valid) {
      const float* src = src0 + k32 * 32;
      v0 = *reinterpret_cast<const float4*>(src);
      v1 = *reinterpret_cast<const float4*>(src + 4);
    }
    ss += v0.x * v0.x + v0.y * v0.y + v0.z * v0.z + v0.w * v0.w
        + v1.x * v1.x + v1.y * v1.y + v1.z * v1.z + v1.w * v1.w;
    ushort4 o0, o1;
    o0.x = f2bf(v0.x); o0.y = f2bf(v0.y); o0.z = f2bf(v0.z); o0.w = f2bf(v0.w);
    o1.x = f2bf(v1.x); o1.y = f2bf(v1.y); o1.z = f2bf(v1.z); o1.w = f2bf(v1.w);
    unsigned short* dst = dst0 + (size_t)k32 * 4 * 512;
    *reinterpret_cast<ushort4*>(dst) = o0;
    *reinterpret_cast<ushort4*>(dst + 4) = o1;
  }
  ss += __shfl_xor(ss, 16);
  ss += __shfl_xor(ss, 32);
  if (q == 0) w1[(size_t)c * WPAD + m] = sqrtf(ss);
}

// ---- prep: imgs -> B fragments (rows r>=36 zero) ----
// Layout: ibfF[(((i*32 + k32)*3 + nt)*64 + lane)*8 + j]
//   = imgs[i][r = nt*16 + (lane&15)][k = k32*32 + (lane>>4)*8 + j]
__global__ void k_prep_imgs_frag(const float* __restrict__ imgs,
                                 unsigned short* __restrict__ ibfF) {
  const int k32 = blockIdx.x;
  const int i = blockIdx.y;
  const int t = threadIdx.x;          // 0..191
  const int nt = t >> 6;
  const int lane = t & 63;
  const int r = nt * 16 + (lane & 15);
  const int k0 = k32 * 32 + (lane >> 4) * 8;
  float4 v0 = make_float4(0.f, 0.f, 0.f, 0.f), v1 = v0;
  if (r < NREG) {
    const float* src = imgs + ((size_t)i * NREG + r) * DIM + k0;
    v0 = *reinterpret_cast<const float4*>(src);
    v1 = *reinterpret_cast<const float4*>(src + 4);
  }
  ushort4 o0, o1;
  o0.x = f2bf(v0.x); o0.y = f2bf(v0.y); o0.z = f2bf(v0.z); o0.w = f2bf(v0.w);
  o1.x = f2bf(v1.x); o1.y = f2bf(v1.y); o1.z = f2bf(v1.z); o1.w = f2bf(v1.w);
  unsigned short* dst = ibfF + ((size_t)(((i * 32 + k32) * 3 + nt) * 64 + lane)) * 8;
  *reinterpret_cast<ushort4*>(dst) = o0;
  *reinterpret_cast<ushort4*>(dst + 4) = o1;
}

// ---- prep: Gram -> off-diag bf16 G'[i][48][64] (rows/cols>=36 and diag zero) + fp32 diag[i][48] ----
__device__ __forceinline__ void pairDecode(int p, int& r, int& c) {
  r = 0;
  while (p >= NREG - r) { p -= NREG - r; ++r; }
  c = r + p;
}

__global__ void k_gram(const float* __restrict__ imgs, unsigned short* __restrict__ gbf,
                       float* __restrict__ gdiag) {
  __shared__ float tile[NREG * 129];
  const int i = blockIdx.x;
  const int t = threadIdx.x;
  unsigned short* g = gbf + (size_t)i * (48 * 64);
  for (int idx = t; idx < 48 * 64; idx += 256) {
    int rr = idx >> 6, cc = idx & 63;
    if (rr >= NREG || cc >= NREG || rr == cc) g[idx] = 0;
  }
  if (t >= NREG && t < 48) gdiag[(size_t)i * 48 + t] = 0.f;

  const int NP = NREG * (NREG + 1) / 2;   // 666 pairs (incl. diag)
  int r0 = 0, q0 = 0, r1 = 0, q1 = 0, r2 = 0, q2 = 0;
  const bool v0 = (t < NP), v1 = (t + 256 < NP), v2 = (t + 512 < NP);
  if (v0) pairDecode(t, r0, q0);
  if (v1) pairDecode(t + 256, r1, q1);
  if (v2) pairDecode(t + 512, r2, q2);
  float s0 = 0.f, s1 = 0.f, s2 = 0.f;
  for (int kk = 0; kk < DIM; kk += 128) {
    __syncthreads();
    for (int idx = t; idx < NREG * 128; idx += 256) {
      int r = idx >> 7, k = idx & 127;
      tile[r * 129 + k] = imgs[((size_t)i * NREG + r) * DIM + kk + k];
    }
    __syncthreads();
    for (int k = 0; k < 128; ++k) {
      if (v0) s0 += tile[r0 * 129 + k] * tile[q0 * 129 + k];
      if (v1) s1 += tile[r1 * 129 + k] * tile[q1 * 129 + k];
      if (v2) s2 += tile[r2 * 129 + k] * tile[q2 * 129 + k];
    }
  }
  float* d = gdiag + (size_t)i * 48;
  if (v0) { if (r0 == q0) d[r0] = s0; else { unsigned short b = f2bf(s0); g[r0 * 64 + q0] = b; g[q0 * 64 + r0] = b; } }
  if (v1) { if (r1 == q1) d[r1] = s1; else { unsigned short b = f2bf(s1); g[r1 * 64 + q1] = b; g[q1 * 64 + r1] = b; } }
  if (v2) { if (r2 == q2) d[r2] = s2; else { unsigned short b = f2bf(s2); g[r2 * 64 + q2] = b; g[q2 * 64 + r2] = b; } }
}

// ---- K-loop: straight-line, 3-stage register pipeline, templated on MLIM ----
template <int MLIM>
__device__ __forceinline__ void kloopT(const unsigned short* __restrict__ aBase,
                                       const unsigned short* __restrict__ b0Base,
                                       const unsigned short* __restrict__ b1Base,
                                       f32x4 (&acc)[4][6]) {
  bf16x8 fa[3][MLIM], fb[3][6];
  auto load = [&](int k32, int buf) __attribute__((always_inline)) {
#pragma unroll
    for (int nt = 0; nt < 3; ++nt) {
      fb[buf][nt]     = *reinterpret_cast<const bf16x8*>(b0Base + ((size_t)k32 * 3 + nt) * 512);
      fb[buf][3 + nt] = *reinterpret_cast<const bf16x8*>(b1Base + ((size_t)k32 * 3 + nt) * 512);
    }
#pragma unroll
    for (int mt = 0; mt < MLIM; ++mt)
      fa[buf][mt] = *reinterpret_cast<const bf16x8*>(aBase + ((size_t)k32 * 4 + mt) * 512);
  };
  auto compute = [&](int buf) __attribute__((always_inline)) {
#pragma unroll
    for (int mt = 0; mt < MLIM; ++mt)
#pragma unroll
      for (int nt = 0; nt < 6; ++nt)
        acc[mt][nt] = __builtin_amdgcn_mfma_f32_16x16x32_bf16(fa[buf][mt], fb[buf][nt], acc[mt][nt], 0, 0, 0);
  };
  load(0, 0);
  load(1, 1);
#pragma unroll
  for (int k32 = 0; k32 < 32; ++k32) {
    if (k32 + 2 < 32) load(k32 + 2, (k32 + 2) % 3);
    compute(k32 % 3);
  }
}

// ---- main fused kernel ----
// Grid (I/2, C/2), block 128 = 2 waves. Wave wv: caption c = 2*blockIdx.y+wv,
// images i0, i0+1 (shared across the 2 waves -> partner B-frags hit L1).
// Per-wave S tile: M=16*mlim (dynamic), N=96, K=1024. K-loop: no LDS, no barriers.
__launch_bounds__(128, 2)
__global__ void k_main(const unsigned short* __restrict__ qbfF,
                       const unsigned short* __restrict__ ibfF,
                       const float* __restrict__ w1,
                       const unsigned short* __restrict__ gbf,
                       const float* __restrict__ gdiag,
                       const int* __restrict__ cap_lens,
                       float* __restrict__ out) {
  __shared__ struct {
    unsigned short attn[2][64 * 64];  // bf16 rows [w][64], swizzled; wave-private
    float w12[2][64];
    float w2d[2][64];
    float w2x[2][64];
  } lds;                               // 17920 B
  const int tid = threadIdx.x;
  const int lane = tid & 63;
  const int wv = tid >> 6;
  const int l15 = lane & 15;
  const int quad = lane >> 4;
  const int i0 = blockIdx.x * 2;
  const int c = blockIdx.y * 2 + wv;
  const int clen = cap_lens[c];
  const int mlim = (clen + 15) >> 4;   // 1..4 valid A-tiles

  f32x4 acc[4][6];
  const f32x4 zero4 = {0.f, 0.f, 0.f, 0.f};
#pragma unroll
  for (int mt = 0; mt < 4; ++mt)
#pragma unroll
    for (int nt = 0; nt < 6; ++nt) acc[mt][nt] = zero4;

  const unsigned short* aBase = qbfF + ((size_t)c * 32 * 4) * 512 + lane * 8;
  const unsigned short* b0Base = ibfF + ((size_t)i0 * 32 * 3) * 512 + lane * 8;
  const unsigned short* b1Base = ibfF + ((size_t)(i0 + 1) * 32 * 3) * 512 + lane * 8;

  switch (mlim) {
    case 1: kloopT<1>(aBase, b0Base, b1Base, acc); break;
    case 2: kloopT<2>(aBase, b0Base, b1Base, acc); break;
    case 3: kloopT<3>(aBase, b0Base, b1Base, acc); break;
    default: kloopT<4>(aBase, b0Base, b1Base, acc); break;
  }

  // ---- epilogue (all LDS below is wave-private; no cross-wave barriers) ----
  {
    uint4* ab = reinterpret_cast<uint4*>(&lds.attn[wv][0]);
    const uint4 z4 = make_uint4(0, 0, 0, 0);
    for (int j = lane; j < 512; j += 64) ab[j] = z4;   // zero incl. K-pad cols 48..63
  }

  const int lo = l15 & 7, hi = l15 >> 3;

#pragma unroll
  for (int img = 0; img < 2; ++img) {
    const int gimg = i0 + img;
    const float* dg = gdiag + (size_t)gimg * 48;
    const float d0 = dg[l15];
    const float d1 = dg[16 + l15];
    const float d2 = dg[32 + l15];
    // per-region l2 norm over w (C-layout: rows live across quads -> xor 16,32)
    float scale[3];
#pragma unroll
    for (int nt3 = 0; nt3 < 3; ++nt3) {
      const int nt = img * 3 + nt3;
      float p = 0.f;
#pragma unroll
      for (int mt = 0; mt < 4; ++mt)
        if (mt < mlim)
#pragma unroll
          for (int rg = 0; rg < 4; ++rg) {
            float s = acc[mt][nt][rg];
            float l = s < 0.f ? 0.1f * s : s;
            p += l * l;
          }
      p += __shfl_xor(p, 16);
      p += __shfl_xor(p, 32);
      scale[nt3] = 9.0f / (sqrtf(p) + 1e-8f);   // SMOOTH folded in
    }
    const bool vr2 = (l15 < 4);   // r = 32+l15 valid only if < 36
    // softmax over r (cols across the 16 lanes of a quad -> xor 1..8), w12, diag, attn->LDS
#pragma unroll
    for (int mt = 0; mt < 4; ++mt) {
      if (mt >= mlim) continue;
#pragma unroll
      for (int rg = 0; rg < 4; ++rg) {
        const float s0 = acc[mt][img * 3 + 0][rg];
        const float s1 = acc[mt][img * 3 + 1][rg];
        const float s2 = acc[mt][img * 3 + 2][rg];
        const float t0 = (s0 < 0.f ? 0.1f * s0 : s0) * scale[0];
        const float t1 = (s1 < 0.f ? 0.1f * s1 : s1) * scale[1];
        const float t2 = (s2 < 0.f ? 0.1f * s2 : s2) * scale[2];
        float mx = fmaxf(t0, t1);
        if (vr2) mx = fmaxf(mx, t2);
        mx = fmaxf(mx, __shfl_xor(mx, 1));
        mx = fmaxf(mx, __shfl_xor(mx, 2));
        mx = fmaxf(mx, __shfl_xor(mx, 4));
        mx = fmaxf(mx, __shfl_xor(mx, 8));
        const float e0 = __expf(t0 - mx);
        const float e1 = __expf(t1 - mx);
        const float e2 = vr2 ? __expf(t2 - mx) : 0.f;
        float sm = e0 + e1 + e2;
        sm += __shfl_xor(sm, 1);
        sm += __shfl_xor(sm, 2);
        sm += __shfl_xor(sm, 4);
        sm += __shfl_xor(sm, 8);
        const float inv = 1.0f / sm;
        const float a0 = e0 * inv, a1 = e1 * inv, a2 = e2 * inv;   // a2==0 when invalid
        float wp = a0 * s0 + a1 * s1 + a2 * s2;                    // w12 uses RAW s
        float dd = a0 * a0 * d0 + a1 * a1 * d1 + a2 * a2 * d2;     // exact diag term
        wp += __shfl_xor(wp, 1); wp += __shfl_xor(wp, 2);
        wp += __shfl_xor(wp, 4); wp += __shfl_xor(wp, 8);
        dd += __shfl_xor(dd, 1); dd += __shfl_xor(dd, 2);
        dd += __shfl_xor(dd, 4); dd += __shfl_xor(dd, 8);
        const int w = mt * 16 + quad * 4 + rg;
        const int w7 = w & 7;
        unsigned short* arow = &lds.attn[wv][w * 64];
        arow[(((0 + hi) ^ w7) << 3) + lo] = f2bf(a0);
        arow[(((2 + hi) ^ w7) << 3) + lo] = f2bf(a1);
        arow[(((4 + hi) ^ w7) << 3) + lo] = f2bf(a2);
        if (l15 == 0) { lds.w12[wv][w] = wp; lds.w2d[wv][w] = dd; }
      }
    }
    // Y = Attn x G' via MFMA (wave-private; in-wave lgkmcnt ordering suffices).
    // G' B-fragments straight from global (hot in L2; 1.5 MB table).
    bf16x8 gfrag[3][2];
#pragma unroll
    for (int nt = 0; nt < 3; ++nt)
#pragma unroll
      for (int ks = 0; ks < 2; ++ks)
        gfrag[nt][ks] = *reinterpret_cast<const bf16x8*>(
            gbf + ((size_t)gimg * 48 + nt * 16 + l15) * 64 + ((ks * 4 + quad) << 3));
#pragma unroll
    for (int mt = 0; mt < 4; ++mt) {
      if (mt >= mlim) continue;
      bf16x8 af[2];
#pragma unroll
      for (int ks = 0; ks < 2; ++ks)
        af[ks] = *reinterpret_cast<const bf16x8*>(
            &lds.attn[wv][(mt * 16 + l15) * 64 + (((ks * 4 + quad) ^ (l15 & 7)) << 3)]);
      f32x4 Y[3] = {zero4, zero4, zero4};
#pragma unroll
      for (int nt = 0; nt < 3; ++nt)
#pragma unroll
        for (int ks = 0; ks < 2; ++ks)
          Y[nt] = __builtin_amdgcn_mfma_f32_16x16x32_bf16(af[ks], gfrag[nt][ks], Y[nt], 0, 0, 0);
      // cross term: w2x[w] = sum_{r'} a[w][r'] * Y[w][r']  (Y C-layout == a C-layout)
#pragma unroll
      for (int rg = 0; rg < 4; ++rg) {
        const int w = mt * 16 + quad * 4 + rg;
        const int w7 = w & 7;
        float p = 0.f;
#pragma unroll
        for (int nt = 0; nt < 3; ++nt) {
          const unsigned short b = lds.attn[wv][w * 64 + (((nt * 2 + hi) ^ w7) << 3) + lo];
          p += __uint_as_float((unsigned)b << 16) * Y[nt][rg];
        }
        p += __shfl_xor(p, 1); p += __shfl_xor(p, 2);
        p += __shfl_xor(p, 4); p += __shfl_xor(p, 8);
        if (l15 == 0) lds.w2x[wv][w] = p;
      }
    }
    // final: lane = word
    float simv = 0.f;
    if (lane < clen) {
      const float w2sq = fmaxf(lds.w2x[wv][lane] + lds.w2d[wv][lane], 0.f);
      const float w2v = sqrtf(w2sq);
      const float w12v = lds.w12[wv][lane];
      const float w1v = w1[(size_t)c * WPAD + lane];
      simv = w12v / fmaxf(w1v * w2v, 1e-8f);
    }
    simv += __shfl_xor(simv, 1);
    simv += __shfl_xor(simv, 2);
    simv += __shfl_xor(simv, 4);
    simv += __shfl_xor(simv, 8);
    simv += __shfl_xor(simv, 16);
    simv += __shfl_xor(simv, 32);
    if (lane == 0) out[(size_t)gimg * NCAP + c] = simv / (float)clen;
  }
}

extern "C" void kernel_launch(void* const* d_in, const int* in_sizes, int n_in,
                              void* d_out, int out_size, void* d_ws, size_t ws_size,
                              hipStream_t stream) {
  const float* imgs = (const float*)d_in[0];
  const float* caps = (const float*)d_in[1];
  const int* cap_lens = (const int*)d_in[3];   // img_lens (d_in[2]) unused by reference
  float* out = (float*)d_out;

  char* ws = (char*)d_ws;
  const size_t QBF_B = (size_t)NCAP * 32 * 4 * 512 * 2;      // 33,554,432
  const size_t IBF_B = (size_t)NIMG * 32 * 3 * 512 * 2;      // 25,165,824
  const size_t W1_B = (size_t)NCAP * WPAD * 4;               // 65,536
  const size_t GBF_B = (size_t)NIMG * 48 * 64 * 2;           // 1,572,864
  unsigned short* qbfF = (unsigned short*)ws;
  unsigned short* ibfF = (unsigned short*)(ws + QBF_B);
  float* w1 = (float*)(ws + QBF_B + IBF_B);
  unsigned short* gbf = (unsigned short*)(ws + QBF_B + IBF_B + W1_B);
  float* gdiag = (float*)(ws + QBF_B + IBF_B + W1_B + GBF_B);

  k_prep_caps_frag<<<NCAP, 256, 0, stream>>>(caps, cap_lens, qbfF, w1);
  k_prep_imgs_frag<<<dim3(32, NIMG), 192, 0, stream>>>(imgs, ibfF);
  k_gram<<<NIMG, 256, 0, stream>>>(imgs, gbf, gdiag);
  k_main<<<dim3(NIMG / 2, NCAP / 2), 128, 0, stream>>>(qbfF, ibfF, w1, gbf, gdiag, cap_lens, out);
}

// Round 10
// 778.023 us; speedup vs baseline: 1.1744x; 1.1744x over previous
//
#include <hip/hip_runtime.h>

// T2ICrossAttentionPool on MI355X.
// Identities: w12[c,i,w] = sum_r attn*Sraw;  |wctx|^2 = a^T G a with
//   G = exact fp32 diag (register math) + off-diag G' bf16 (MFMA quadratic form).
// R9 post-mortem: "3-stage pipeline" never materialized (VGPR 88 — compiler
//   collapsed it; HIP can't pin prefetch distance), fused prep lost ~30us.
// R10: attack L2 latency with TLP instead of pipeline depth. Wave = 1 cap x
//   1 img: acc 12 tiles = 48 regs -> total ~119 regs -> 4 waves/SIMD
//   (launch_bounds(256,4), 16 waves/CU, 2x TLP). Block = 4 waves = 2 caps x
//   2 imgs (pairs share A/B fragments via L1). Prep reverted to R8 split form.

#define NIMG 256
#define NREG 36
#define DIM 1024
#define NCAP 256
#define MAXW 60
#define WPAD 64

typedef short bf16x8 __attribute__((ext_vector_type(8)));
typedef float f32x4 __attribute__((ext_vector_type(4)));

__device__ __forceinline__ unsigned short f2bf(float f) {
  unsigned u = __float_as_uint(f);
  u += 0x7FFF + ((u >> 16) & 1);   // round-to-nearest-even
  return (unsigned short)(u >> 16);
}

// ---- prep: w1[c][w] = ||masked q row|| ----
__global__ void k_prep_w1(const float* __restrict__ caps, const int* __restrict__ cap_lens,
                          float* __restrict__ w1) {
  const int bid = blockIdx.x;          // c*64 + w
  const int c = bid >> 6;
  const int w = bid & 63;
  const int t = threadIdx.x;
  const bool valid = (w < MAXW) && (w < cap_lens[c]);
  float4 v = make_float4(0.f, 0.f, 0.f, 0.f);
  if (valid) v = *reinterpret_cast<const float4*>(caps + ((size_t)c * MAXW + w) * DIM + t * 4);
  float ss = v.x * v.x + v.y * v.y + v.z * v.z + v.w * v.w;
#pragma unroll
  for (int m = 1; m <= 32; m <<= 1) ss += __shfl_xor(ss, m);
  __shared__ float part[4];
  if ((t & 63) == 0) part[t >> 6] = ss;
  __syncthreads();
  if (t == 0) w1[bid] = sqrtf(part[0] + part[1] + part[2] + part[3]);
}

// ---- prep: caps -> A fragments, masked (rows w>=clen zero) ----
// Layout: qbfF[(((c*32 + k32)*4 + mt)*64 + lane)*8 + j]
//   = q[c][m = mt*16 + (lane&15)][k = k32*32 + (lane>>4)*8 + j]
__global__ void k_prep_caps_frag(const float* __restrict__ caps, const int* __restrict__ cap_lens,
                                 unsigned short* __restrict__ qbfF) {
  const int k32 = blockIdx.x;
  const int c = blockIdx.y;
  const int t = threadIdx.x;
  const int mt = t >> 6;
  const int lane = t & 63;
  const int m = mt * 16 + (lane & 15);
  const int k0 = k32 * 32 + (lane >> 4) * 8;
  const int clen = cap_lens[c];
  float4 v0 = make_float4(0.f, 0.f, 0.f, 0.f), v1 = v0;
  if (m < clen && m < MAXW) {
    const float* src = caps + ((size_t)c * MAXW + m) * DIM + k0;
    v0 = *reinterpret_cast<const float4*>(src);
    v1 = *reinterpret_cast<const float4*>(src + 4);
  }
  ushort4 o0, o1;
  o0.x = f2bf(v0.x); o0.y = f2bf(v0.y); o0.z = f2bf(v0.z); o0.w = f2bf(v0.w);
  o1.x = f2bf(v1.x); o1.y = f2bf(v1.y); o1.z = f2bf(v1.z); o1.w = f2bf(v1.w);
  unsigned short* dst = qbfF + ((size_t)(((c * 32 + k32) * 4 + mt) * 64 + lane)) * 8;
  *reinterpret_cast<ushort4*>(dst) = o0;
  *reinterpret_cast<ushort4*>(dst + 4) = o1;
}

// ---- prep: imgs -> B fragments (rows r>=36 zero) ----
// Layout: ibfF[(((i*32 + k32)*3 + nt)*64 + lane)*8 + j]
//   = imgs[i][r = nt*16 + (lane&15)][k = k32*32 + (lane>>4)*8 + j]
__global__ void k_prep_imgs_frag(const float* __restrict__ imgs,
                                 unsigned short* __restrict__ ibfF) {
  const int k32 = blockIdx.x;
  const int i = blockIdx.y;
  const int t = threadIdx.x;          // 0..191
  const int nt = t >> 6;
  const int lane = t & 63;
  const int r = nt * 16 + (lane & 15);
  const int k0 = k32 * 32 + (lane >> 4) * 8;
  float4 v0 = make_float4(0.f, 0.f, 0.f, 0.f), v1 = v0;
  if (r < NREG) {
    const float* src = imgs + ((size_t)i * NREG + r) * DIM + k0;
    v0 = *reinterpret_cast<const float4*>(src);
    v1 = *reinterpret_cast<const float4*>(src + 4);
  }
  ushort4 o0, o1;
  o0.x = f2bf(v0.x); o0.y = f2bf(v0.y); o0.z = f2bf(v0.z); o0.w = f2bf(v0.w);
  o1.x = f2bf(v1.x); o1.y = f2bf(v1.y); o1.z = f2bf(v1.z); o1.w = f2bf(v1.w);
  unsigned short* dst = ibfF + ((size_t)(((i * 32 + k32) * 3 + nt) * 64 + lane)) * 8;
  *reinterpret_cast<ushort4*>(dst) = o0;
  *reinterpret_cast<ushort4*>(dst + 4) = o1;
}

// ---- prep: Gram -> off-diag bf16 G'[i][48][64] (rows/cols>=36 and diag zero) + fp32 diag[i][48] ----
__device__ __forceinline__ void pairDecode(int p, int& r, int& c) {
  r = 0;
  while (p >= NREG - r) { p -= NREG - r; ++r; }
  c = r + p;
}

__global__ void k_gram(const float* __restrict__ imgs, unsigned short* __restrict__ gbf,
                       float* __restrict__ gdiag) {
  __shared__ float tile[NREG * 129];
  const int i = blockIdx.x;
  const int t = threadIdx.x;
  unsigned short* g = gbf + (size_t)i * (48 * 64);
  for (int idx = t; idx < 48 * 64; idx += 256) {
    int rr = idx >> 6, cc = idx & 63;
    if (rr >= NREG || cc >= NREG || rr == cc) g[idx] = 0;
  }
  if (t >= NREG && t < 48) gdiag[(size_t)i * 48 + t] = 0.f;

  const int NP = NREG * (NREG + 1) / 2;   // 666 pairs (incl. diag)
  int r0 = 0, q0 = 0, r1 = 0, q1 = 0, r2 = 0, q2 = 0;
  const bool v0 = (t < NP), v1 = (t + 256 < NP), v2 = (t + 512 < NP);
  if (v0) pairDecode(t, r0, q0);
  if (v1) pairDecode(t + 256, r1, q1);
  if (v2) pairDecode(t + 512, r2, q2);
  float s0 = 0.f, s1 = 0.f, s2 = 0.f;
  for (int kk = 0; kk < DIM; kk += 128) {
    __syncthreads();
    for (int idx = t; idx < NREG * 128; idx += 256) {
      int r = idx >> 7, k = idx & 127;
      tile[r * 129 + k] = imgs[((size_t)i * NREG + r) * DIM + kk + k];
    }
    __syncthreads();
    for (int k = 0; k < 128; ++k) {
      if (v0) s0 += tile[r0 * 129 + k] * tile[q0 * 129 + k];
      if (v1) s1 += tile[r1 * 129 + k] * tile[q1 * 129 + k];
      if (v2) s2 += tile[r2 * 129 + k] * tile[q2 * 129 + k];
    }
  }
  float* d = gdiag + (size_t)i * 48;
  if (v0) { if (r0 == q0) d[r0] = s0; else { unsigned short b = f2bf(s0); g[r0 * 64 + q0] = b; g[q0 * 64 + r0] = b; } }
  if (v1) { if (r1 == q1) d[r1] = s1; else { unsigned short b = f2bf(s1); g[r1 * 64 + q1] = b; g[q1 * 64 + r1] = b; } }
  if (v2) { if (r2 == q2) d[r2] = s2; else { unsigned short b = f2bf(s2); g[r2 * 64 + q2] = b; g[q2 * 64 + r2] = b; } }
}

// ---- K-loop: straight-line, 2-stage register double-buffer, templated on MLIM ----
template <int MLIM>
__device__ __forceinline__ void kloopT(const unsigned short* __restrict__ aBase,
                                       const unsigned short* __restrict__ bBase,
                                       f32x4 (&acc)[4][3]) {
  bf16x8 fa[2][MLIM], fb[2][3];
  auto load = [&](int k32, int buf) __attribute__((always_inline)) {
#pragma unroll
    for (int nt = 0; nt < 3; ++nt)
      fb[buf][nt] = *reinterpret_cast<const bf16x8*>(bBase + ((size_t)k32 * 3 + nt) * 512);
#pragma unroll
    for (int mt = 0; mt < MLIM; ++mt)
      fa[buf][mt] = *reinterpret_cast<const bf16x8*>(aBase + ((size_t)k32 * 4 + mt) * 512);
  };
  auto compute = [&](int buf) __attribute__((always_inline)) {
#pragma unroll
    for (int mt = 0; mt < MLIM; ++mt)
#pragma unroll
      for (int nt = 0; nt < 3; ++nt)
        acc[mt][nt] = __builtin_amdgcn_mfma_f32_16x16x32_bf16(fa[buf][mt], fb[buf][nt], acc[mt][nt], 0, 0, 0);
  };
  load(0, 0);
#pragma unroll
  for (int k32 = 0; k32 < 32; ++k32) {
    if (k32 + 1 < 32) load(k32 + 1, (k32 + 1) & 1);
    compute(k32 & 1);
  }
}

// ---- main fused kernel ----
// Grid (I/2, C/2), block 256 = 4 waves. Wave wv: caption c0+(wv&1), image
// i0+(wv>>1) -> wave pairs share A and B fragment lines via L1.
// Per-wave S tile: M=16*mlim (dynamic), N=48, K=1024. No LDS/barriers in K-loop.
__launch_bounds__(256, 4)
__global__ void k_main(const unsigned short* __restrict__ qbfF,
                       const unsigned short* __restrict__ ibfF,
                       const float* __restrict__ w1,
                       const unsigned short* __restrict__ gbf,
                       const float* __restrict__ gdiag,
                       const int* __restrict__ cap_lens,
                       float* __restrict__ out) {
  __shared__ struct {
    unsigned short attn[4][64 * 64];  // bf16 rows [w][64], swizzled; wave-private
    float w12[4][64];
    float w2d[4][64];
    float w2x[4][64];
  } lds;                               // 35840 B -> 4 blocks/CU
  const int tid = threadIdx.x;
  const int lane = tid & 63;
  const int wv = tid >> 6;
  const int l15 = lane & 15;
  const int quad = lane >> 4;
  const int i0 = blockIdx.x * 2;
  const int c = blockIdx.y * 2 + (wv & 1);
  const int img = i0 + (wv >> 1);
  const int clen = cap_lens[c];
  const int mlim = (clen + 15) >> 4;   // 1..4 valid A-tiles

  f32x4 acc[4][3];
  const f32x4 zero4 = {0.f, 0.f, 0.f, 0.f};
#pragma unroll
  for (int mt = 0; mt < 4; ++mt)
#pragma unroll
    for (int nt = 0; nt < 3; ++nt) acc[mt][nt] = zero4;

  const unsigned short* aBase = qbfF + ((size_t)c * 32 * 4) * 512 + lane * 8;
  const unsigned short* bBase = ibfF + ((size_t)img * 32 * 3) * 512 + lane * 8;

  switch (mlim) {
    case 1: kloopT<1>(aBase, bBase, acc); break;
    case 2: kloopT<2>(aBase, bBase, acc); break;
    case 3: kloopT<3>(aBase, bBase, acc); break;
    default: kloopT<4>(aBase, bBase, acc); break;
  }

  // ---- epilogue (all LDS below is wave-private; no cross-wave barriers) ----
  {
    uint4* ab = reinterpret_cast<uint4*>(&lds.attn[wv][0]);
    const uint4 z4 = make_uint4(0, 0, 0, 0);
    for (int j = lane; j < 512; j += 64) ab[j] = z4;   // zero incl. K-pad cols 48..63
  }

  const int lo = l15 & 7, hi = l15 >> 3;
  const float* dg = gdiag + (size_t)img * 48;
  const float d0 = dg[l15];
  const float d1 = dg[16 + l15];
  const float d2 = dg[32 + l15];

  // per-region l2 norm over w (C-layout: rows live across quads -> xor 16,32)
  float scale[3];
#pragma unroll
  for (int nt = 0; nt < 3; ++nt) {
    float p = 0.f;
#pragma unroll
    for (int mt = 0; mt < 4; ++mt)
      if (mt < mlim)
#pragma unroll
        for (int rg = 0; rg < 4; ++rg) {
          float s = acc[mt][nt][rg];
          float l = s < 0.f ? 0.1f * s : s;
          p += l * l;
        }
    p += __shfl_xor(p, 16);
    p += __shfl_xor(p, 32);
    scale[nt] = 9.0f / (sqrtf(p) + 1e-8f);   // SMOOTH folded in
  }
  const bool vr2 = (l15 < 4);   // r = 32+l15 valid only if < 36
  // softmax over r (cols across the 16 lanes of a quad -> xor 1..8), w12, diag, attn->LDS
#pragma unroll
  for (int mt = 0; mt < 4; ++mt) {
    if (mt >= mlim) continue;
#pragma unroll
    for (int rg = 0; rg < 4; ++rg) {
      const float s0 = acc[mt][0][rg];
      const float s1 = acc[mt][1][rg];
      const float s2 = acc[mt][2][rg];
      const float t0 = (s0 < 0.f ? 0.1f * s0 : s0) * scale[0];
      const float t1 = (s1 < 0.f ? 0.1f * s1 : s1) * scale[1];
      const float t2 = (s2 < 0.f ? 0.1f * s2 : s2) * scale[2];
      float mx = fmaxf(t0, t1);
      if (vr2) mx = fmaxf(mx, t2);
      mx = fmaxf(mx, __shfl_xor(mx, 1));
      mx = fmaxf(mx, __shfl_xor(mx, 2));
      mx = fmaxf(mx, __shfl_xor(mx, 4));
      mx = fmaxf(mx, __shfl_xor(mx, 8));
      const float e0 = __expf(t0 - mx);
      const float e1 = __expf(t1 - mx);
      const float e2 = vr2 ? __expf(t2 - mx) : 0.f;
      float sm = e0 + e1 + e2;
      sm += __shfl_xor(sm, 1);
      sm += __shfl_xor(sm, 2);
      sm += __shfl_xor(sm, 4);
      sm += __shfl_xor(sm, 8);
      const float inv = 1.0f / sm;
      const float a0 = e0 * inv, a1 = e1 * inv, a2 = e2 * inv;   // a2==0 when invalid
      float wp = a0 * s0 + a1 * s1 + a2 * s2;                    // w12 uses RAW s
      float dd = a0 * a0 * d0 + a1 * a1 * d1 + a2 * a2 * d2;     // exact diag term
      wp += __shfl_xor(wp, 1); wp += __shfl_xor(wp, 2);
      wp += __shfl_xor(wp, 4); wp += __shfl_xor(wp, 8);
      dd += __shfl_xor(dd, 1); dd += __shfl_xor(dd, 2);
      dd += __shfl_xor(dd, 4); dd += __shfl_xor(dd, 8);
      const int w = mt * 16 + quad * 4 + rg;
      const int w7 = w & 7;
      unsigned short* arow = &lds.attn[wv][w * 64];
      arow[(((0 + hi) ^ w7) << 3) + lo] = f2bf(a0);
      arow[(((2 + hi) ^ w7) << 3) + lo] = f2bf(a1);
      arow[(((4 + hi) ^ w7) << 3) + lo] = f2bf(a2);
      if (l15 == 0) { lds.w12[wv][w] = wp; lds.w2d[wv][w] = dd; }
    }
  }
  // Y = Attn x G' via MFMA (wave-private; in-wave lgkmcnt ordering suffices).
  // G' B-fragments straight from global (hot in L2; 1.5 MB table).
  bf16x8 gfrag[3][2];
#pragma unroll
  for (int nt = 0; nt < 3; ++nt)
#pragma unroll
    for (int ks = 0; ks < 2; ++ks)
      gfrag[nt][ks] = *reinterpret_cast<const bf16x8*>(
          gbf + ((size_t)img * 48 + nt * 16 + l15) * 64 + ((ks * 4 + quad) << 3));
#pragma unroll
  for (int mt = 0; mt < 4; ++mt) {
    if (mt >= mlim) continue;
    bf16x8 af[2];
#pragma unroll
    for (int ks = 0; ks < 2; ++ks)
      af[ks] = *reinterpret_cast<const bf16x8*>(
          &lds.attn[wv][(mt * 16 + l15) * 64 + (((ks * 4 + quad) ^ (l15 & 7)) << 3)]);
    f32x4 Y[3] = {zero4, zero4, zero4};
#pragma unroll
    for (int nt = 0; nt < 3; ++nt)
#pragma unroll
      for (int ks = 0; ks < 2; ++ks)
        Y[nt] = __builtin_amdgcn_mfma_f32_16x16x32_bf16(af[ks], gfrag[nt][ks], Y[nt], 0, 0, 0);
    // cross term: w2x[w] = sum_{r'} a[w][r'] * Y[w][r']  (Y C-layout == a C-layout)
#pragma unroll
    for (int rg = 0; rg < 4; ++rg) {
      const int w = mt * 16 + quad * 4 + rg;
      const int w7 = w & 7;
      float p = 0.f;
#pragma unroll
      for (int nt = 0; nt < 3; ++nt) {
        const unsigned short b = lds.attn[wv][w * 64 + (((nt * 2 + hi) ^ w7) << 3) + lo];
        p += __uint_as_float((unsigned)b << 16) * Y[nt][rg];
      }
      p += __shfl_xor(p, 1); p += __shfl_xor(p, 2);
      p += __shfl_xor(p, 4); p += __shfl_xor(p, 8);
      if (l15 == 0) lds.w2x[wv][w] = p;
    }
  }
  // final: lane = word
  float simv = 0.f;
  if (lane < clen) {
    const float w2sq = fmaxf(lds.w2x[wv][lane] + lds.w2d[wv][lane], 0.f);
    const float w2v = sqrtf(w2sq);
    const float w12v = lds.w12[wv][lane];
    const float w1v = w1[(size_t)c * WPAD + lane];
    simv = w12v / fmaxf(w1v * w2v, 1e-8f);
  }
  simv += __shfl_xor(simv, 1);
  simv += __shfl_xor(simv, 2);
  simv += __shfl_xor(simv, 4);
  simv += __shfl_xor(simv, 8);
  simv += __shfl_xor(simv, 16);
  simv += __shfl_xor(simv, 32);
  if (lane == 0) out[(size_t)img * NCAP + c] = simv / (float)clen;
}

extern "C" void kernel_launch(void* const* d_in, const int* in_sizes, int n_in,
                              void* d_out, int out_size, void* d_ws, size_t ws_size,
                              hipStream_t stream) {
  const float* imgs = (const float*)d_in[0];
  const float* caps = (const float*)d_in[1];
  const int* cap_lens = (const int*)d_in[3];   // img_lens (d_in[2]) unused by reference
  float* out = (float*)d_out;

  char* ws = (char*)d_ws;
  const size_t QBF_B = (size_t)NCAP * 32 * 4 * 512 * 2;      // 33,554,432
  const size_t IBF_B = (size_t)NIMG * 32 * 3 * 512 * 2;      // 25,165,824
  const size_t W1_B = (size_t)NCAP * WPAD * 4;               // 65,536
  const size_t GBF_B = (size_t)NIMG * 48 * 64 * 2;           // 1,572,864
  unsigned short* qbfF = (unsigned short*)ws;
  unsigned short* ibfF = (unsigned short*)(ws + QBF_B);
  float* w1 = (float*)(ws + QBF_B + IBF_B);
  unsigned short* gbf = (unsigned short*)(ws + QBF_B + IBF_B + W1_B);
  float* gdiag = (float*)(ws + QBF_B + IBF_B + W1_B + GBF_B);

  k_prep_w1<<<NCAP * WPAD, 256, 0, stream>>>(caps, cap_lens, w1);
  k_prep_caps_frag<<<dim3(32, NCAP), 256, 0, stream>>>(caps, cap_lens, qbfF);
  k_prep_imgs_frag<<<dim3(32, NIMG), 192, 0, stream>>>(imgs, ibfF);
  k_gram<<<NIMG, 256, 0, stream>>>(imgs, gbf, gdiag);
  k_main<<<dim3(NIMG / 2, NCAP / 2), 256, 0, stream>>>(qbfF, ibfF, w1, gbf, gdiag, cap_lens, out);
}